// Round 1
// baseline (1113.943 us; speedup 1.0000x reference)
//
#include <hip/hip_runtime.h>
#include <hip/hip_bf16.h>

#define B_   128
#define C_   2048
#define S_   196
#define HID_ 1024
#define T_   20

typedef __attribute__((ext_vector_type(8))) short s16x8;   // 8 bf16 (4 VGPRs)
typedef __attribute__((ext_vector_type(4))) float f32x4_t; // MFMA 16x16 acc

__device__ __forceinline__ float fast_tanh(float x) {
  // tanh(x) = 1 - 2/(e^{2x}+1); exp overflow -> inf -> 1, underflow -> 0 -> -1. OK.
  float e = __expf(2.f * x);
  return 1.f - 2.f / (e + 1.f);
}

// ---------------- fp32 -> bf16 weight convert (n % 4 == 0) ----------------
__global__ void cvt_k(const float* __restrict__ in, __hip_bfloat16* __restrict__ out, int n) {
  int i = (blockIdx.x * 256 + threadIdx.x) * 4;
  if (i >= n) return;
  float4 v = *(const float4*)(in + i);
  out[i + 0] = __float2bfloat16(v.x);
  out[i + 1] = __float2bfloat16(v.y);
  out[i + 2] = __float2bfloat16(v.z);
  out[i + 3] = __float2bfloat16(v.w);
}

// ---------------- v_i [b,c,s] fp32 -> viT [b,s,c] bf16 ----------------
__global__ void transpose_k(const float* __restrict__ src, __hip_bfloat16* __restrict__ dst) {
  __shared__ float tile[32][33];           // +1 pad breaks bank conflicts
  int b  = blockIdx.z;
  int c0 = blockIdx.x * 32;
  int s0 = blockIdx.y * 32;
  int tid = threadIdx.x;
  int tj = tid & 31, ti = tid >> 5;
  const float* sp = src + ((size_t)b * C_ + c0) * S_ + s0;
  #pragma unroll
  for (int p = 0; p < 4; p++) {
    int i = ti + p * 8;
    int s = s0 + tj;
    tile[i][tj] = (s < S_) ? sp[(size_t)i * S_ + tj] : 0.f;
  }
  __syncthreads();
  int cp = tid & 15, si = tid >> 4;
  #pragma unroll
  for (int p = 0; p < 2; p++) {
    int srow = si + p * 16;
    int s = s0 + srow;
    if (s < S_) {
      __hip_bfloat162 v;
      v.x = __float2bfloat16(tile[cp * 2][srow]);
      v.y = __float2bfloat16(tile[cp * 2 + 1][srow]);
      *(__hip_bfloat162*)(dst + ((size_t)b * S_ + s) * C_ + c0 + cp * 2) = v;
    }
  }
}

// ---------------- u[b,h] = mean_t v_q[b,t,h] ----------------
__global__ void umean_k(const float* __restrict__ vq, float* __restrict__ u) {
  int b = blockIdx.y;
  int h = blockIdx.x * 256 + threadIdx.x;
  const float* p = vq + (size_t)b * T_ * HID_ + h;
  float s = 0.f;
  #pragma unroll
  for (int t = 0; t < T_; t++) s += p[t * HID_];
  u[(size_t)b * HID_ + h] = s * (1.f / T_);
}

// ---------------- vqt[b,k] = sum_h u[b,h]*w_u[k,h] + b_u[k]  (fp32, small) ----------------
__global__ void vqt_k(const float* __restrict__ u, const float* __restrict__ wu,
                      const float* __restrict__ bu, float* __restrict__ out) {
  __shared__ float us[32][64];   // [b][h]
  __shared__ float ws[64][65];   // [k][h], +1 pad (row stride 65 -> 2-way max, free)
  int k0 = blockIdx.x * 64, b0 = blockIdx.y * 32;
  int tid = threadIdx.x;
  int kl = tid & 63, bg = tid >> 6;
  float acc[8];
  #pragma unroll
  for (int j = 0; j < 8; j++) acc[j] = 0.f;
  for (int h0 = 0; h0 < HID_; h0 += 64) {
    __syncthreads();
    for (int idx = tid; idx < 32 * 16; idx += 256) {
      int bi = idx >> 4, jj = (idx & 15) * 4;
      *(float4*)&us[bi][jj] = *(const float4*)&u[(size_t)(b0 + bi) * HID_ + h0 + jj];
    }
    for (int idx = tid; idx < 64 * 16; idx += 256) {
      int ki = idx >> 4, jj = (idx & 15) * 4;
      float4 v = *(const float4*)&wu[(size_t)(k0 + ki) * HID_ + h0 + jj];
      ws[ki][jj] = v.x; ws[ki][jj + 1] = v.y; ws[ki][jj + 2] = v.z; ws[ki][jj + 3] = v.w;
    }
    __syncthreads();
    #pragma unroll 8
    for (int h = 0; h < 64; h++) {
      float wv = ws[kl][h];
      #pragma unroll
      for (int j = 0; j < 8; j++) acc[j] += wv * us[bg * 8 + j][h];  // us: wave-broadcast
    }
  }
  #pragma unroll
  for (int j = 0; j < 8; j++)
    out[(size_t)(b0 + bg * 8 + j) * HID_ + k0 + kl] = acc[j] + bu[k0 + kl];
}

// ---------------- main GEMM: out[s, n] = sum_k A[b,s,k] * W[n,k]  ----------------
// Orientation: M = s (208 = 13x16 tiles, 196 valid), N = 128 cols/block, K = KDIM.
// A = viT (l1) or vi (hop): [b][s][K], rows K-contiguous -> natural A fragments.
// W = bf16 weights [N=1024][K] row-major -> natural B fragments.
// l1 epilogue: tanh(acc + bias[col]) -> vi[b,s,col] bf16.
// hop epilogue: tanh(acc + vqt[b,col]) -> softmax over s (in-block: per-lane + shfl_xor
//               over the 4 lanes sharing a column) -> u[b,col] += sum_s p * vi[b,s,col].
template<int KDIM, bool IS_HOP>
__global__ __launch_bounds__(256, 2)
void gemm_k(const __hip_bfloat16* __restrict__ Asrc,
            const __hip_bfloat16* __restrict__ Bw,
            const float* __restrict__ aux,      // l1: bias[1024]; hop: vqt[B][1024]
            __hip_bfloat16* __restrict__ vi,    // l1: output; hop: input for epilogue
            float* __restrict__ u) {            // hop only: in/out [B][1024]
  constexpr int MS = 13;                        // 13 m-subtiles of 16 -> 208 rows
  __shared__ short a_lds[832 * 8];              // [quad(k-half8)][208 rows][8 bf16]
  __shared__ short b_lds[512 * 8];              // [quad][128 rows][8 bf16]
  const int b  = blockIdx.y;
  const int n0 = blockIdx.x * 128;
  const int tid  = threadIdx.x;
  const int wv   = tid >> 6;
  const int lane = tid & 63;
  const int ln   = lane & 15;
  const int quad = lane >> 4;

  const short* Ab = (const short*)(Asrc + (size_t)b * S_ * KDIM);
  const short* Bb = (const short*)Bw + (size_t)n0 * KDIM;

  f32x4_t acc[MS][2] = {};

  for (int k0 = 0; k0 < KDIM; k0 += 32) {
    __syncthreads();
    // stage A tile [208 rows x 32 k] = 832 16B chunks; consecutive tid -> 64B contiguous
    #pragma unroll
    for (int p = 0; p < 4; p++) {
      int i = tid + p * 256;
      if (i < 832) {
        int m = i >> 2, q = i & 3;
        int mg = (m < S_) ? m : (S_ - 1);      // clamp pad rows (outputs masked later)
        s16x8 v = *(const s16x8*)(Ab + (size_t)mg * KDIM + k0 + q * 8);
        *(s16x8*)&a_lds[(q * 208 + m) * 8] = v;
      }
    }
    // stage B tile [128 rows x 32 k] = 512 chunks
    #pragma unroll
    for (int p = 0; p < 2; p++) {
      int i = tid + p * 256;
      int n = i >> 2, q = i & 3;
      s16x8 v = *(const s16x8*)(Bb + (size_t)n * KDIM + k0 + q * 8);
      *(s16x8*)&b_lds[(q * 128 + n) * 8] = v;
    }
    __syncthreads();
    s16x8 bf0 = *(s16x8*)&b_lds[(quad * 128 + wv * 32 + ln) * 8];
    s16x8 bf1 = *(s16x8*)&b_lds[(quad * 128 + wv * 32 + 16 + ln) * 8];
    #pragma unroll
    for (int ms = 0; ms < MS; ms++) {
      s16x8 af = *(s16x8*)&a_lds[(quad * 208 + ms * 16 + ln) * 8];
      acc[ms][0] = __builtin_amdgcn_mfma_f32_16x16x32_bf16(af, bf0, acc[ms][0], 0, 0, 0);
      acc[ms][1] = __builtin_amdgcn_mfma_f32_16x16x32_bf16(af, bf1, acc[ms][1], 0, 0, 0);
    }
  }

  // C/D layout (m89-verified): col = lane&15, row = (lane>>4)*4 + reg
  const int col0 = n0 + wv * 32 + ln;
  const int col1 = col0 + 16;
  if (!IS_HOP) {
    float bias0 = aux[col0], bias1 = aux[col1];
    #pragma unroll
    for (int ms = 0; ms < MS; ms++) {
      #pragma unroll
      for (int r = 0; r < 4; r++) {
        int row = ms * 16 + quad * 4 + r;
        if (row < S_) {
          vi[((size_t)b * S_ + row) * HID_ + col0] =
              __float2bfloat16(fast_tanh(acc[ms][0][r] + bias0));
          vi[((size_t)b * S_ + row) * HID_ + col1] =
              __float2bfloat16(fast_tanh(acc[ms][1][r] + bias1));
        }
      }
    }
  } else {
    float vq0 = aux[(size_t)b * HID_ + col0];
    float vq1 = aux[(size_t)b * HID_ + col1];
    float mx0 = -1e30f, mx1 = -1e30f;
    #pragma unroll
    for (int ms = 0; ms < MS; ms++) {
      #pragma unroll
      for (int r = 0; r < 4; r++) {
        int row = ms * 16 + quad * 4 + r;
        float v0, v1;
        if (row < S_) {
          v0 = fast_tanh(acc[ms][0][r] + vq0);
          v1 = fast_tanh(acc[ms][1][r] + vq1);
        } else { v0 = -1e30f; v1 = -1e30f; }
        acc[ms][0][r] = v0; acc[ms][1][r] = v1;
        mx0 = fmaxf(mx0, v0); mx1 = fmaxf(mx1, v1);
      }
    }
    // column = fixed lane&15; its 208 rows live in lanes {ln, ln^16, ln^32, ln^48}
    mx0 = fmaxf(mx0, __shfl_xor(mx0, 16)); mx0 = fmaxf(mx0, __shfl_xor(mx0, 32));
    mx1 = fmaxf(mx1, __shfl_xor(mx1, 16)); mx1 = fmaxf(mx1, __shfl_xor(mx1, 32));
    float den0 = 0.f, num0 = 0.f, den1 = 0.f, num1 = 0.f;
    const __hip_bfloat16* vb = vi + (size_t)b * S_ * HID_;
    #pragma unroll
    for (int ms = 0; ms < MS; ms++) {
      #pragma unroll
      for (int r = 0; r < 4; r++) {
        int row = ms * 16 + quad * 4 + r;
        if (row < S_) {
          float e0 = __expf(acc[ms][0][r] - mx0);
          float e1 = __expf(acc[ms][1][r] - mx1);
          den0 += e0; den1 += e1;
          num0 += e0 * __bfloat162float(vb[(size_t)row * HID_ + col0]);
          num1 += e1 * __bfloat162float(vb[(size_t)row * HID_ + col1]);
        }
      }
    }
    den0 += __shfl_xor(den0, 16); den0 += __shfl_xor(den0, 32);
    num0 += __shfl_xor(num0, 16); num0 += __shfl_xor(num0, 32);
    den1 += __shfl_xor(den1, 16); den1 += __shfl_xor(den1, 32);
    num1 += __shfl_xor(num1, 16); num1 += __shfl_xor(num1, 32);
    if (quad == 0) {
      u[(size_t)b * HID_ + col0] += num0 / den0;
      u[(size_t)b * HID_ + col1] += num1 / den1;
    }
  }
}

extern "C" void kernel_launch(void* const* d_in, const int* in_sizes, int n_in,
                              void* d_out, int out_size, void* d_ws, size_t ws_size,
                              hipStream_t stream) {
  const float* v_i   = (const float*)d_in[0];
  const float* v_q   = (const float*)d_in[1];
  const float* l1_w  = (const float*)d_in[2];
  const float* l1_b  = (const float*)d_in[3];
  const float* w_vi0 = (const float*)d_in[4];
  const float* w_u0  = (const float*)d_in[5];
  const float* b_u0  = (const float*)d_in[6];
  const float* w_vi1 = (const float*)d_in[7];
  const float* w_u1  = (const float*)d_in[8];
  const float* b_u1  = (const float*)d_in[9];
  float* u = (float*)d_out;                       // u lives in d_out throughout

  // workspace layout (~163 MB): viT | vi | vqt | bf16 weights
  __hip_bfloat16* viT  = (__hip_bfloat16*)d_ws;                    // [B][S][C]
  __hip_bfloat16* vi   = viT + (size_t)B_ * S_ * C_;               // [B][S][HID]
  float*          vqt  = (float*)(vi + (size_t)B_ * S_ * HID_);    // [B][HID]
  __hip_bfloat16* l1wb = (__hip_bfloat16*)(vqt + (size_t)B_ * HID_);
  __hip_bfloat16* wv0b = l1wb + (size_t)HID_ * C_;
  __hip_bfloat16* wv1b = wv0b + (size_t)HID_ * HID_;

  cvt_k<<<dim3((HID_ * C_) / 1024), 256, 0, stream>>>(l1_w, l1wb, HID_ * C_);
  cvt_k<<<dim3((HID_ * HID_) / 1024), 256, 0, stream>>>(w_vi0, wv0b, HID_ * HID_);
  cvt_k<<<dim3((HID_ * HID_) / 1024), 256, 0, stream>>>(w_vi1, wv1b, HID_ * HID_);
  transpose_k<<<dim3(C_ / 32, 7, B_), 256, 0, stream>>>(v_i, viT);
  umean_k<<<dim3(HID_ / 256, B_), 256, 0, stream>>>(v_q, u);

  gemm_k<C_, false><<<dim3(8, B_), 256, 0, stream>>>(viT, l1wb, l1_b, vi, nullptr);

  vqt_k<<<dim3(16, 4), 256, 0, stream>>>(u, w_u0, b_u0, vqt);
  gemm_k<HID_, true><<<dim3(8, B_), 256, 0, stream>>>(vi, wv0b, vqt, vi, u);

  vqt_k<<<dim3(16, 4), 256, 0, stream>>>(u, w_u1, b_u1, vqt);
  gemm_k<HID_, true><<<dim3(8, B_), 256, 0, stream>>>(vi, wv1b, vqt, vi, u);
}

// Round 2
// 824.200 us; speedup vs baseline: 1.3515x; 1.3515x over previous
//
#include <hip/hip_runtime.h>
#include <hip/hip_bf16.h>

#define B_   128
#define C_   2048
#define S_   196
#define HID_ 1024
#define T_   20

typedef __attribute__((ext_vector_type(8))) short s16x8;   // 8 bf16 (4 VGPRs)
typedef __attribute__((ext_vector_type(4))) float f32x4_t; // MFMA 16x16 acc
typedef __attribute__((ext_vector_type(4))) unsigned short us4;

__device__ __forceinline__ float fast_tanh(float x) {
  float e = __expf(2.f * x);
  return 1.f - 2.f / (e + 1.f);
}
__device__ __forceinline__ unsigned short f2bf(float x) {
  __hip_bfloat16 h = __float2bfloat16(x);
  return *reinterpret_cast<unsigned short*>(&h);
}
// async 16B global->LDS (width=16). LDS dest is wave-uniform base + lane*16,
// so the LDS slot index must be linear in lane — our staging loops guarantee it.
__device__ __forceinline__ void gl_lds16(const short* g, short* l) {
  __builtin_amdgcn_global_load_lds(
      (const __attribute__((address_space(1))) void*)g,
      (__attribute__((address_space(3))) void*)l, 16, 0, 0);
}

// ---------------- fp32 -> bf16 weight convert (n % 4 == 0) ----------------
__global__ void cvt_k(const float* __restrict__ in, __hip_bfloat16* __restrict__ out, int n) {
  int i = (blockIdx.x * 256 + threadIdx.x) * 4;
  if (i >= n) return;
  float4 v = *(const float4*)(in + i);
  out[i + 0] = __float2bfloat16(v.x);
  out[i + 1] = __float2bfloat16(v.y);
  out[i + 2] = __float2bfloat16(v.z);
  out[i + 3] = __float2bfloat16(v.w);
}

// ---------------- v_i [b,c,s] fp32 -> viT [b,s,c] bf16 (vectorized) ----------------
// tile: 64 c-rows x 32 s. float4 loads (S_=196 divisible by 4), ushort4 stores.
__global__ void transpose_k(const float* __restrict__ src, __hip_bfloat16* __restrict__ dst) {
  __shared__ float tile[32][65];               // [s][c], stride 65 -> 2-way max (free)
  int b  = blockIdx.z;
  int c0 = blockIdx.x * 64;
  int s0 = blockIdx.y * 32;
  int t  = threadIdx.x;
  int cl = t >> 3, sq = t & 7;                 // load: 4 s per lane
  const float* sp = src + ((size_t)b * C_ + c0) * S_ + s0;
  #pragma unroll
  for (int p = 0; p < 2; p++) {
    int c = cl + p * 32;
    int s = sq * 4;
    if (s0 + s < S_) {
      float4 v = *(const float4*)(sp + (size_t)c * S_ + s);
      tile[s + 0][c] = v.x; tile[s + 1][c] = v.y;
      tile[s + 2][c] = v.z; tile[s + 3][c] = v.w;
    }
  }
  __syncthreads();
  int sl = t >> 4, cq = t & 15;                // store: 4 c per lane (8B)
  #pragma unroll
  for (int p = 0; p < 2; p++) {
    int s = sl + p * 16;
    if (s0 + s < S_) {
      us4 v;
      v.x = f2bf(tile[s][cq * 4 + 0]); v.y = f2bf(tile[s][cq * 4 + 1]);
      v.z = f2bf(tile[s][cq * 4 + 2]); v.w = f2bf(tile[s][cq * 4 + 3]);
      *(us4*)(dst + ((size_t)b * S_ + s0 + s) * C_ + c0 + cq * 4) = v;
    }
  }
}

// ---------------- u[b,h] = mean_t v_q[b,t,h] ----------------
__global__ void umean_k(const float* __restrict__ vq, float* __restrict__ u) {
  int b = blockIdx.y;
  int h = blockIdx.x * 256 + threadIdx.x;
  const float* p = vq + (size_t)b * T_ * HID_ + h;
  float s = 0.f;
  #pragma unroll
  for (int t = 0; t < T_; t++) s += p[t * HID_];
  u[(size_t)b * HID_ + h] = s * (1.f / T_);
}

// ---------------- vqt[b,k] = sum_h u[b,h]*w_u[k,h] + b_u[k] ----------------
__global__ void vqt_k(const float* __restrict__ u, const float* __restrict__ wu,
                      const float* __restrict__ bu, float* __restrict__ out) {
  __shared__ float us[32][64];
  __shared__ float ws[64][65];
  int k0 = blockIdx.x * 64, b0 = blockIdx.y * 32;
  int tid = threadIdx.x;
  int kl = tid & 63, bg = tid >> 6;
  float acc[8];
  #pragma unroll
  for (int j = 0; j < 8; j++) acc[j] = 0.f;
  for (int h0 = 0; h0 < HID_; h0 += 64) {
    __syncthreads();
    for (int idx = tid; idx < 32 * 16; idx += 256) {
      int bi = idx >> 4, jj = (idx & 15) * 4;
      *(float4*)&us[bi][jj] = *(const float4*)&u[(size_t)(b0 + bi) * HID_ + h0 + jj];
    }
    for (int idx = tid; idx < 64 * 16; idx += 256) {
      int ki = idx >> 4, jj = (idx & 15) * 4;
      float4 v = *(const float4*)&wu[(size_t)(k0 + ki) * HID_ + h0 + jj];
      ws[ki][jj] = v.x; ws[ki][jj + 1] = v.y; ws[ki][jj + 2] = v.z; ws[ki][jj + 3] = v.w;
    }
    __syncthreads();
    #pragma unroll 8
    for (int h = 0; h < 64; h++) {
      float wv = ws[kl][h];
      #pragma unroll
      for (int j = 0; j < 8; j++) acc[j] += wv * us[bg * 8 + j][h];
    }
  }
  #pragma unroll
  for (int j = 0; j < 8; j++)
    out[(size_t)(b0 + bg * 8 + j) * HID_ + k0 + kl] = acc[j] + bu[k0 + kl];
}

// ---------------- main GEMM: out[s,n] = sum_k A[b,s,k] * W[n,k] ----------------
// Block tile M=208(196 valid) x N=128, BK=32, 4 waves (wave N=32).
// LDS: row-major tiles of 16B chunks, slot = row*4 + (q ^ ((row>>1)&3)) XOR-swizzle:
//   staging is linear in lane (global_load_lds requirement), fragment ds_read_b128
//   lands 2-way bank aliasing only (free).
// Grid: 1D 1024, swizzled so each b's 8 n-blocks sit in a 32-id window on 2 XCDs
//   (A fetched ~2x not 8x) and each XCD's weight working set is 4 slices (L2-fits).
template<int KDIM, bool IS_HOP>
__global__ __launch_bounds__(256, 3)
void gemm_k(const __hip_bfloat16* __restrict__ Asrc,
            const __hip_bfloat16* __restrict__ Bw,
            const float* __restrict__ aux,
            __hip_bfloat16* __restrict__ vi,
            float* __restrict__ u) {
  constexpr int MS = 13;
  __shared__ short a_lds[832 * 8];             // 208 rows x 4 chunk-slots x 8 bf16
  __shared__ short b_lds[512 * 8];             // 128 rows x 4 chunk-slots x 8 bf16
  const int id = blockIdx.x;
  const int b  = (id & 3) | ((id >> 5) << 2);
  const int n0 = (((id >> 2) & 1) | (((id >> 3) & 3) << 1)) * 128;
  const int tid  = threadIdx.x;
  const int wv   = tid >> 6;
  const int lane = tid & 63;
  const int ln   = lane & 15;
  const int quad = lane >> 4;
  const int qsw  = quad ^ ((ln >> 1) & 3);     // fragment slot swizzle (ms/wv-invariant)

  const short* Ab = (const short*)(Asrc + (size_t)b * S_ * KDIM);
  const short* Bb = (const short*)Bw + (size_t)n0 * KDIM;

  f32x4_t acc[MS][2] = {};

  for (int k0 = 0; k0 < KDIM; k0 += 32) {
    __syncthreads();
    // A tile: 832 chunks; chunk slot i holds global k-chunk q = (i&3)^((i>>3)&3)
    #pragma unroll
    for (int p = 0; p < 4; p++) {
      int i = tid + p * 256;
      if (i < 832) {
        int m = i >> 2;
        int q = (i & 3) ^ ((i >> 3) & 3);
        int mg = (m < S_) ? m : (S_ - 1);
        gl_lds16(Ab + (size_t)mg * KDIM + k0 + q * 8, &a_lds[i * 8]);
      }
    }
    // B tile: 512 chunks
    #pragma unroll
    for (int p = 0; p < 2; p++) {
      int i = tid + p * 256;
      int n = i >> 2;
      int q = (i & 3) ^ ((i >> 3) & 3);
      gl_lds16(Bb + (size_t)n * KDIM + k0 + q * 8, &b_lds[i * 8]);
    }
    __syncthreads();
    s16x8 bf0 = *(s16x8*)&b_lds[((wv * 32 + ln) * 4 + qsw) * 8];
    s16x8 bf1 = *(s16x8*)&b_lds[((wv * 32 + 16 + ln) * 4 + qsw) * 8];
    #pragma unroll
    for (int ms = 0; ms < MS; ms++) {
      s16x8 af = *(s16x8*)&a_lds[((ms * 16 + ln) * 4 + qsw) * 8];
      acc[ms][0] = __builtin_amdgcn_mfma_f32_16x16x32_bf16(af, bf0, acc[ms][0], 0, 0, 0);
      acc[ms][1] = __builtin_amdgcn_mfma_f32_16x16x32_bf16(af, bf1, acc[ms][1], 0, 0, 0);
    }
  }

  // C/D layout: col = lane&15, row = quad*4 + reg
  const int col0 = n0 + wv * 32 + ln;
  const int col1 = col0 + 16;
  if (!IS_HOP) {
    float bias0 = aux[col0], bias1 = aux[col1];
    #pragma unroll
    for (int ms = 0; ms < MS; ms++) {
      #pragma unroll
      for (int r = 0; r < 4; r++) {
        int row = ms * 16 + quad * 4 + r;
        if (row < S_) {
          vi[((size_t)b * S_ + row) * HID_ + col0] =
              __float2bfloat16(fast_tanh(acc[ms][0][r] + bias0));
          vi[((size_t)b * S_ + row) * HID_ + col1] =
              __float2bfloat16(fast_tanh(acc[ms][1][r] + bias1));
        }
      }
    }
  } else {
    float vq0 = aux[(size_t)b * HID_ + col0];
    float vq1 = aux[(size_t)b * HID_ + col1];
    float mx0 = -1e30f, mx1 = -1e30f;
    #pragma unroll
    for (int ms = 0; ms < MS; ms++) {
      #pragma unroll
      for (int r = 0; r < 4; r++) {
        int row = ms * 16 + quad * 4 + r;
        float v0, v1;
        if (row < S_) {
          v0 = fast_tanh(acc[ms][0][r] + vq0);
          v1 = fast_tanh(acc[ms][1][r] + vq1);
        } else { v0 = -1e30f; v1 = -1e30f; }
        acc[ms][0][r] = v0; acc[ms][1][r] = v1;
        mx0 = fmaxf(mx0, v0); mx1 = fmaxf(mx1, v1);
      }
    }
    mx0 = fmaxf(mx0, __shfl_xor(mx0, 16)); mx0 = fmaxf(mx0, __shfl_xor(mx0, 32));
    mx1 = fmaxf(mx1, __shfl_xor(mx1, 16)); mx1 = fmaxf(mx1, __shfl_xor(mx1, 32));
    float den0 = 0.f, num0 = 0.f, den1 = 0.f, num1 = 0.f;
    const __hip_bfloat16* vb = vi + (size_t)b * S_ * HID_;
    #pragma unroll
    for (int ms = 0; ms < MS; ms++) {
      #pragma unroll
      for (int r = 0; r < 4; r++) {
        int row = ms * 16 + quad * 4 + r;
        if (row < S_) {
          float e0 = __expf(acc[ms][0][r] - mx0);
          float e1 = __expf(acc[ms][1][r] - mx1);
          den0 += e0; den1 += e1;
          num0 += e0 * __bfloat162float(vb[(size_t)row * HID_ + col0]);
          num1 += e1 * __bfloat162float(vb[(size_t)row * HID_ + col1]);
        }
      }
    }
    den0 += __shfl_xor(den0, 16); den0 += __shfl_xor(den0, 32);
    num0 += __shfl_xor(num0, 16); num0 += __shfl_xor(num0, 32);
    den1 += __shfl_xor(den1, 16); den1 += __shfl_xor(den1, 32);
    num1 += __shfl_xor(num1, 16); num1 += __shfl_xor(num1, 32);
    if (quad == 0) {
      u[(size_t)b * HID_ + col0] += num0 / den0;
      u[(size_t)b * HID_ + col1] += num1 / den1;
    }
  }
}

extern "C" void kernel_launch(void* const* d_in, const int* in_sizes, int n_in,
                              void* d_out, int out_size, void* d_ws, size_t ws_size,
                              hipStream_t stream) {
  const float* v_i   = (const float*)d_in[0];
  const float* v_q   = (const float*)d_in[1];
  const float* l1_w  = (const float*)d_in[2];
  const float* l1_b  = (const float*)d_in[3];
  const float* w_vi0 = (const float*)d_in[4];
  const float* w_u0  = (const float*)d_in[5];
  const float* b_u0  = (const float*)d_in[6];
  const float* w_vi1 = (const float*)d_in[7];
  const float* w_u1  = (const float*)d_in[8];
  const float* b_u1  = (const float*)d_in[9];
  float* u = (float*)d_out;

  __hip_bfloat16* viT  = (__hip_bfloat16*)d_ws;                    // [B][S][C]
  __hip_bfloat16* vi   = viT + (size_t)B_ * S_ * C_;               // [B][S][HID]
  float*          vqt  = (float*)(vi + (size_t)B_ * S_ * HID_);    // [B][HID]
  __hip_bfloat16* l1wb = (__hip_bfloat16*)(vqt + (size_t)B_ * HID_);
  __hip_bfloat16* wv0b = l1wb + (size_t)HID_ * C_;
  __hip_bfloat16* wv1b = wv0b + (size_t)HID_ * HID_;

  cvt_k<<<dim3((HID_ * C_) / 1024), 256, 0, stream>>>(l1_w, l1wb, HID_ * C_);
  cvt_k<<<dim3((HID_ * HID_) / 1024), 256, 0, stream>>>(w_vi0, wv0b, HID_ * HID_);
  cvt_k<<<dim3((HID_ * HID_) / 1024), 256, 0, stream>>>(w_vi1, wv1b, HID_ * HID_);
  transpose_k<<<dim3(C_ / 64, 7, B_), 256, 0, stream>>>(v_i, viT);
  umean_k<<<dim3(HID_ / 256, B_), 256, 0, stream>>>(v_q, u);

  gemm_k<C_, false><<<dim3(1024), 256, 0, stream>>>(viT, l1wb, l1_b, vi, nullptr);

  vqt_k<<<dim3(16, 4), 256, 0, stream>>>(u, w_u0, b_u0, vqt);
  gemm_k<HID_, true><<<dim3(1024), 256, 0, stream>>>(vi, wv0b, vqt, vi, u);

  vqt_k<<<dim3(16, 4), 256, 0, stream>>>(u, w_u1, b_u1, vqt);
  gemm_k<HID_, true><<<dim3(1024), 256, 0, stream>>>(vi, wv1b, vqt, vi, u);
}